// Round 7
// baseline (398.050 us; speedup 1.0000x reference)
//
#include <hip/hip_runtime.h>
#include <cstdint>
#include <cmath>

typedef _Float16 f16;
using f16x8 = __attribute__((ext_vector_type(8))) _Float16;
using f16x4 = __attribute__((ext_vector_type(4))) _Float16;
using f32x4 = __attribute__((ext_vector_type(4))) float;

#define NHEAD 16
#define SEQ   2048
#define KS    2            // K-split for k_pv / Opart
#define KSS   4            // K-split for k_stats
#define NEG_INF -3.0e38f

static __device__ __forceinline__ f32x4 mfma16(f16x8 a, f16x8 b, f32x4 c) {
    return __builtin_amdgcn_mfma_f32_16x16x32_f16(a, b, c, 0, 0, 0);
}

static __device__ __forceinline__ void gload16(const void* gp, void* lp) {
    __builtin_amdgcn_global_load_lds(
        (const __attribute__((address_space(1))) unsigned int*)gp,
        (__attribute__((address_space(3))) unsigned int*)lp, 16, 0, 0);
}

// ---------------- fused f32 -> f16 conversion of all 6 tensors ----------------
__global__ __launch_bounds__(256) void k_cvt_all(
    const float* __restrict__ hsrc, const float* __restrict__ qdw, const float* __restrict__ kvdw,
    const float* __restrict__ quw, const float* __restrict__ kuw, const float* __restrict__ ow,
    f16* __restrict__ h16, f16* __restrict__ dw16, f16* __restrict__ quw16,
    f16* __restrict__ kuw16, f16* __restrict__ ow16)
{
    constexpr int C1 = 1048576;            // h: 4194304
    constexpr int C2 = C1 + 786432;        // qdw: 3145728
    constexpr int C3 = C2 + 327680;        // kvdw: 1310720 total (1179648 valid)
    constexpr int C4 = C3 + 1179648;       // quw: 4718592
    constexpr int C5 = C4 + 524288;        // kuw: 2097152
    int chunk = blockIdx.x * 256 + threadIdx.x;
    const float* src; f16* dst; int off; int nvalid;
    if (chunk < C1)      { src = hsrc; dst = h16;  off = chunk;      nvalid = 4194304; }
    else if (chunk < C2) { src = qdw;  dst = dw16; off = chunk - C1; nvalid = 3145728; }
    else if (chunk < C3) { src = kvdw; dst = dw16 + 3145728; off = chunk - C2; nvalid = 1179648; }
    else if (chunk < C4) { src = quw;  dst = quw16; off = chunk - C3; nvalid = 4718592; }
    else if (chunk < C5) { src = kuw;  dst = kuw16; off = chunk - C4; nvalid = 2097152; }
    else                 { src = ow;   dst = ow16;  off = chunk - C5; nvalid = 4194304; }
    int i = off * 4;
    f16x4 o;
#pragma unroll
    for (int k = 0; k < 4; k++) {
        int idx = i + k;
        float v = (idx < nvalid) ? src[idx] : 0.f;
        o[k] = (f16)v;
    }
    *(f16x4*)&dst[i] = o;
}

// ---------------- RoPE cos/sin table ----------------
__global__ __launch_bounds__(256) void k_rope_table(float* __restrict__ cs)
{
    int idx = blockIdx.x * 256 + threadIdx.x;   // 65536 total
    int t = idx >> 5;
    int j = idx & 31;
    float invf = (float)pow(10000.0, -(double)j / 32.0);
    float ang  = (float)t * invf;
    cs[t * 64 + j]      = (float)cos((double)ang);
    cs[t * 64 + 32 + j] = (float)sin((double)ang);
}

// ---------------- GEMM body with prefetched double-buffered staging ----------------
// lds: 16384 f16 = A[2][4096] | B[2][4096]
template <typename OutT, bool NT>
static __device__ __forceinline__ void gemm_body(const f16* __restrict__ A, const f16* __restrict__ B,
                                                 OutT* __restrict__ C, int K, int ldc,
                                                 int m0, int n0, int k0, int k1,
                                                 f16* __restrict__ lds)
{
    const int tid  = threadIdx.x;
    const int lane = tid & 63;
    const int wv   = tid >> 6;
    const int l15  = lane & 15;
    const int lg   = lane >> 4;
    const int wm   = (wv >> 1) * 64;
    const int wn   = (wv & 1) * 64;

    f32x4 acc[4][4] = {};

    const int r0  = tid >> 2;
    const int kc0 = (tid & 3) * 8;
    const f16* ap = &A[(size_t)(m0 + r0) * K + kc0];
    const f16* bp = &B[(size_t)(n0 + r0) * K + kc0];

    f16* As[2] = { lds,        lds + 4096 };
    f16* Bs[2] = { lds + 8192, lds + 12288 };

    auto stage = [&](int kt, int buf) {
        gload16(ap + kt,                     As[buf] + wv * 512);
        gload16(ap + (size_t)64 * K + kt,    As[buf] + 2048 + wv * 512);
        gload16(bp + kt,                     Bs[buf] + wv * 512);
        gload16(bp + (size_t)64 * K + kt,    Bs[buf] + 2048 + wv * 512);
    };

    stage(k0, 0);
    __syncthreads();                 // drains vmcnt(0): tile k0 resident
    int cur = 0;
    for (int kt = k0; kt < k1; kt += 32) {
        if (kt + 32 < k1) stage(kt + 32, cur ^ 1);   // prefetch next tile (async)
        f16x8 af[4], bf[4];
#pragma unroll
        for (int i = 0; i < 4; i++)
            af[i] = *(const f16x8*)&As[cur][(wm + i * 16 + l15) * 32 + lg * 8];
#pragma unroll
        for (int i = 0; i < 4; i++)
            bf[i] = *(const f16x8*)&Bs[cur][(wn + i * 16 + l15) * 32 + lg * 8];
#pragma unroll
        for (int i = 0; i < 4; i++)
#pragma unroll
            for (int j = 0; j < 4; j++)
                acc[i][j] = mfma16(af[i], bf[j], acc[i][j]);
        __syncthreads();             // drains vmcnt(0) (prefetch landed) + lgkm
        cur ^= 1;
    }
#pragma unroll
    for (int i = 0; i < 4; i++) {
#pragma unroll
        for (int j = 0; j < 4; j++) {
            const int row = m0 + wm + i * 16 + lg * 4;
            const int col = n0 + wn + j * 16 + l15;
#pragma unroll
            for (int r = 0; r < 4; r++) {
                if constexpr (NT)
                    __builtin_nontemporal_store((OutT)acc[i][j][r], &C[(size_t)(row + r) * ldc + col]);
                else
                    C[(size_t)(row + r) * ldc + col] = (OutT)acc[i][j][r];
            }
        }
    }
}

// generic GEMM with optional K-split (partials at C + z*zstride)
template <typename OutT, bool NT, int SPLITK>
__global__ __launch_bounds__(256) void k_gemm(const f16* __restrict__ A, const f16* __restrict__ B,
                                              OutT* __restrict__ C, int K, int ldc, size_t zstride)
{
    __shared__ __align__(16) f16 lds[16384];
    const int ks   = (SPLITK > 1) ? (int)blockIdx.z : 0;
    const int ksub = K / SPLITK;
    gemm_body<OutT, NT>(A, B, C + (size_t)ks * zstride, K, ldc,
                        blockIdx.y * 128, blockIdx.x * 128, ks * ksub, ks * ksub + ksub, lds);
}

// fused q_up (24 x-tiles) + k_up (32 x-tiles) launch
__global__ __launch_bounds__(256) void k_up_fused(const f16* __restrict__ cq, const f16* __restrict__ quw,
                                                  f16* __restrict__ q_all,
                                                  const f16* __restrict__ lat, const f16* __restrict__ kuw,
                                                  f16* __restrict__ kv_all)
{
    __shared__ __align__(16) f16 lds[16384];
    if (blockIdx.x < 24)
        gemm_body<f16, false>(cq, quw, q_all, 1536, 3072,
                              blockIdx.y * 128, blockIdx.x * 128, 0, 1536, lds);
    else
        gemm_body<f16, false>(lat, kuw, kv_all, 512, 4096,
                              blockIdx.y * 128, (blockIdx.x - 24) * 128, 0, 512, lds);
}

// ---------------- o_proj split-K combine ----------------
__global__ __launch_bounds__(256) void k_add2f(const float* __restrict__ p, float* __restrict__ out)
{
    size_t i = ((size_t)blockIdx.x * 256 + threadIdx.x) * 4;
    f32x4 a = *(const f32x4*)&p[i];
    f32x4 b = *(const f32x4*)&p[(size_t)2048 * 2048 + i];
    __builtin_nontemporal_store(a + b, (f32x4*)&out[i]);
}

// ---------------- fused RMS norms + down split-K combine + k_pe rope ----------------
__global__ __launch_bounds__(256) void k_rms_both(const float* __restrict__ P0, const float* __restrict__ P1,
                                                  const float* __restrict__ wq, const float* __restrict__ wkv,
                                                  f16* __restrict__ cq, f16* __restrict__ lat,
                                                  f16* __restrict__ kro, const float* __restrict__ cs)
{
    const int row = blockIdx.x, tid = threadIdx.x;
    const float* a = &P0[(size_t)row * 2176];
    const float* b = &P1[(size_t)row * 2176];
    float ssq = 0.f, ssk = 0.f;
    for (int c = tid; c < 1536; c += 256) { float v = a[c] + b[c]; ssq += v * v; }
    for (int c = 1536 + tid; c < 2112; c += 256) { float v = a[c] + b[c]; ssk += v * v; }
#pragma unroll
    for (int off = 32; off > 0; off >>= 1) {
        ssq += __shfl_xor(ssq, off);
        ssk += __shfl_xor(ssk, off);
    }
    __shared__ float part[4][2];
    if ((tid & 63) == 0) { part[tid >> 6][0] = ssq; part[tid >> 6][1] = ssk; }
    __syncthreads();
    float totq = part[0][0] + part[1][0] + part[2][0] + part[3][0];
    float totk = part[0][1] + part[1][1] + part[2][1] + part[3][1];
    float scq = 1.f / sqrtf(totq / 1536.f + 1e-6f);
    float sck = 1.f / sqrtf(totk / 576.f + 1e-6f);
    for (int c = tid; c < 1536; c += 256)
        cq[(size_t)row * 1536 + c] = (f16)(wq[c] * (a[c] + b[c]) * scq);
    for (int c = tid; c < 512; c += 256)
        lat[(size_t)row * 512 + c] = (f16)(wkv[c] * (a[1536 + c] + b[1536 + c]) * sck);
    if (tid < 32) {
        int j = tid;
        float va = wkv[512 + 2 * j] * (a[2048 + 2 * j] + b[2048 + 2 * j]) * sck;
        float vb = wkv[512 + 2 * j + 1] * (a[2048 + 2 * j + 1] + b[2048 + 2 * j + 1]) * sck;
        float cv = cs[row * 64 + j], sv = cs[row * 64 + 32 + j];
        kro[row * 64 + j]      = (f16)(va * cv - vb * sv);
        kro[row * 64 + 32 + j] = (f16)(vb * cv + va * sv);
    }
}

// ---------------- assemble Q ----------------
__global__ __launch_bounds__(256) void k_asm_q(const f16* __restrict__ q_all, const float* __restrict__ cs,
                                               f16* __restrict__ Qf)
{
    size_t idx = (size_t)blockIdx.x * 256 + threadIdx.x;
    if (idx >= (size_t)16 * 2048 * 192) return;
    int d = (int)(idx % 192);
    size_t hs = idx / 192;
    int s = (int)(hs % 2048);
    int h = (int)(hs / 2048);
    const f16* qrow = &q_all[(size_t)s * 3072 + h * 192];
    float v;
    if (d < 64) {
        int j = d & 31;
        float a = (float)qrow[128 + 2 * j], b = (float)qrow[128 + 2 * j + 1];
        float cv = cs[s * 64 + j], sv = cs[s * 64 + 32 + j];
        v = (d < 32) ? (a * cv - b * sv) : (b * cv + a * sv);
    } else {
        v = (float)qrow[d - 64];
    }
    Qf[idx] = (f16)v;
}

// ---------------- assemble K_nope + V^T via LDS transpose ----------------
__global__ __launch_bounds__(256) void k_asm_kv(const f16* __restrict__ kv_all,
                                                f16* __restrict__ Knope,  // [16][2048][128]
                                                f16* __restrict__ Vt)     // [16][128][2048]
{
    __shared__ __align__(16) f16 Vs[128][136];
    const int s0 = blockIdx.x * 128;
    const int h  = blockIdx.y;
    const int tid = threadIdx.x;

#pragma unroll
    for (int i = 0; i < 16; i++) {
        const int c = tid + 256 * i;
        const int s_loc = c >> 5;
        const int g = c & 31;
        f16x8 v = *(const f16x8*)&kv_all[(size_t)(s0 + s_loc) * 4096 + h * 256 + g * 8];
        if (g < 16) {
            *(f16x8*)&Knope[((size_t)h * 2048 + s0 + s_loc) * 128 + g * 8] = v;
        } else {
            const int d0 = (g - 16) * 8;
#pragma unroll
            for (int k = 0; k < 8; k++) Vs[d0 + k][s_loc] = v[k];
        }
    }
    __syncthreads();
#pragma unroll
    for (int i = 0; i < 8; i++) {
        const int c = tid + 256 * i;
        const int d = c >> 4;
        const int gs = c & 15;
        f16x8 v = *(const f16x8*)&Vs[d][gs * 8];
        *(f16x8*)&Vt[((size_t)h * 128 + d) * 2048 + s0 + gs * 8] = v;
    }
}

// ---------------- attention 1/4: K-split partial stats, async double-buffered K ----------------
// grid (32 qt, KSS ks, 16 h)
__global__ __launch_bounds__(256) void k_stats(
    const f16* __restrict__ Qf, const f16* __restrict__ Krope, const f16* __restrict__ Knope,
    float* __restrict__ mlpart)   // [16][32][KSS][64][2]
{
    const int h  = blockIdx.z;
    const int ks = blockIdx.y;
    const int qt = blockIdx.x;
    const int q0 = qt * 64;
    const int tid = threadIdx.x;
    const int lane = tid & 63;
    const int wv = tid >> 6;
    const int l15 = lane & 15;
    const int lg  = lane >> 4;
    const int rowb = q0 + wv * 16;

    __shared__ __align__(16) f16 Ks_[2][64][200];

    float m[4], l[4];
#pragma unroll
    for (int r = 0; r < 4; r++) { m[r] = NEG_INF; l[r] = 0.f; }

    if (ks <= qt) {
        f16x8 qf[6];
        {
            const f16* qbase = &Qf[((size_t)h * SEQ + rowb + l15) * 192];
#pragma unroll
            for (int kf = 0; kf < 6; kf++)
                qf[kf] = *(const f16x8*)&qbase[kf * 32 + lg * 8];
        }
        const int srow = tid >> 2;
        const int sp4  = tid & 3;
        const f32x4 vzero = {0.f, 0.f, 0.f, 0.f};

        auto loadK = [&](int c0, f16x8 (&v)[6]) {
#pragma unroll
            for (int i = 0; i < 6; i++) {
                const int p = sp4 + 4 * i;
                if (p < 8) v[i] = *(const f16x8*)&Krope[(size_t)(c0 + srow) * 64 + p * 8];
                else       v[i] = *(const f16x8*)&Knope[((size_t)h * SEQ + c0 + srow) * 128 + (p - 8) * 8];
            }
        };
        auto writeK = [&](f16x8 (&v)[6], int buf) {
#pragma unroll
            for (int i = 0; i < 6; i++) {
                const int p = sp4 + 4 * i;
                *(f16x8*)&Ks_[buf][srow][p * 8] = v[i];
            }
        };

        {
            f16x8 v0[6];
            loadK(ks * 64, v0);
            writeK(v0, 0);
        }
        __syncthreads();
        int cur = 0;
        for (int t = ks; t <= qt; t += KSS) {
            const int c0 = t * 64;
            const bool hasNext = (t + KSS <= qt);
            f16x8 vn[6];
            if (hasNext) loadK((t + KSS) * 64, vn);   // async: latency hides under compute

            f32x4 s[4];
#pragma unroll
            for (int ni = 0; ni < 4; ni++) {
                s[ni] = vzero;
                const f16* kp = &Ks_[cur][ni * 16 + l15][0];
#pragma unroll
                for (int kf = 0; kf < 6; kf++)
                    s[ni] = mfma16(qf[kf], *(const f16x8*)&kp[kf * 32 + lg * 8], s[ni]);
            }

            float vmax[4] = {NEG_INF, NEG_INF, NEG_INF, NEG_INF};
#pragma unroll
            for (int ni = 0; ni < 4; ni++) {
                const int col = c0 + ni * 16 + l15;
#pragma unroll
                for (int r = 0; r < 4; r++) {
                    const int row = rowb + lg * 4 + r;
                    float v = (col <= row) ? s[ni][r] : NEG_INF;
                    s[ni][r] = v;
                    vmax[r] = fmaxf(vmax[r], v);
                }
            }
#pragma unroll
            for (int off = 1; off < 16; off <<= 1)
#pragma unroll
                for (int r = 0; r < 4; r++)
                    vmax[r] = fmaxf(vmax[r], __shfl_xor(vmax[r], off));
#pragma unroll
            for (int r = 0; r < 4; r++) {
                const float nm = fmaxf(m[r], vmax[r]);
                float es = 0.f;
#pragma unroll
                for (int ni = 0; ni < 4; ni++) es += expf(s[ni][r] - nm);
#pragma unroll
                for (int off = 1; off < 16; off <<= 1) es += __shfl_xor(es, off);
                l[r] = l[r] * expf(m[r] - nm) + es;
                m[r] = nm;
            }

            if (hasNext) writeK(vn, cur ^ 1);
            __syncthreads();
            cur ^= 1;
        }
    }

    if (l15 == 0) {
#pragma unroll
        for (int r = 0; r < 4; r++) {
            const int rin = wv * 16 + lg * 4 + r;
            float* mp = &mlpart[((((size_t)h * 32 + qt) * KSS + ks) * 64 + rin) * 2];
            mp[0] = m[r];
            mp[1] = l[r];
        }
    }
}

// ---------------- attention 2/4: merge partial (m,l) -> (m, 1/l) ----------------
__global__ __launch_bounds__(256) void k_mlcomb(const float* __restrict__ mlpart,
                                                float* __restrict__ mlbuf)
{
    int idx = blockIdx.x * 256 + threadIdx.x;      // 16*2048
    if (idx >= 16 * 2048) return;
    int h = idx >> 11, row = idx & 2047;
    int qt = row >> 6, rin = row & 63;
    float mm = NEG_INF;
    float mk[KSS], lk[KSS];
#pragma unroll
    for (int ks = 0; ks < KSS; ks++) {
        const float* mp = &mlpart[((((size_t)h * 32 + qt) * KSS + ks) * 64 + rin) * 2];
        mk[ks] = mp[0]; lk[ks] = mp[1];
        mm = fmaxf(mm, mk[ks]);
    }
    float ll = 0.f;
#pragma unroll
    for (int ks = 0; ks < KSS; ks++) ll += lk[ks] * expf(mk[ks] - mm);
    mlbuf[(size_t)idx * 2]     = mm;
    mlbuf[(size_t)idx * 2 + 1] = 1.f / ll;
}

// ---------------- attention 3/4: P write (nt) + partial O ----------------
__global__ __launch_bounds__(256) void k_pv(
    const f16* __restrict__ Qf, const f16* __restrict__ Krope, const f16* __restrict__ Knope,
    const f16* __restrict__ Vt, const float* __restrict__ mlbuf,
    float* __restrict__ attnw,    // [16][2048][2048] final P
    f16* __restrict__ Opart)      // [KS][2048][2048] partial O
{
    const int h  = blockIdx.z;
    const int ks = blockIdx.y;
    const int qt = blockIdx.x;
    const int q0 = qt * 64;
    const int tid = threadIdx.x;
    const int lane = tid & 63;
    const int wv = tid >> 6;
    const int l15 = lane & 15;
    const int lg  = lane >> 4;
    const int rowb = q0 + wv * 16;

    __shared__ __align__(16) f16 Ks_[64][200];
    __shared__ __align__(16) f16 Vs[128][72];
    __shared__ __align__(16) f16 Plds[4][16][72];

    f16x8 qf[6];
    {
        const f16* qbase = &Qf[((size_t)h * SEQ + rowb + l15) * 192];
#pragma unroll
        for (int kf = 0; kf < 6; kf++)
            qf[kf] = *(const f16x8*)&qbase[kf * 32 + lg * 8];
    }

    float mr[4], rlr[4];
#pragma unroll
    for (int r = 0; r < 4; r++) {
        const int row = rowb + lg * 4 + r;
        mr[r]  = mlbuf[((size_t)h * SEQ + row) * 2];
        rlr[r] = mlbuf[((size_t)h * SEQ + row) * 2 + 1];
    }

    f32x4 o[8] = {};
    const f32x4 vzero = {0.f, 0.f, 0.f, 0.f};
    const int srow = tid >> 2;
    const int sp4  = tid & 3;

    for (int t = ks; t <= qt; t += KS) {
        const int c0 = t * 64;
        __syncthreads();
#pragma unroll
        for (int i = 0; i < 6; i++) {
            const int p = sp4 + 4 * i;
            f16x8 v;
            if (p < 8) v = *(const f16x8*)&Krope[(size_t)(c0 + srow) * 64 + p * 8];
            else       v = *(const f16x8*)&Knope[((size_t)h * SEQ + c0 + srow) * 128 + (p - 8) * 8];
            *(f16x8*)&Ks_[srow][p * 8] = v;
        }
#pragma unroll
        for (int i = 0; i < 4; i++) {
            const int c = tid + 256 * i;
            const int d = c >> 3, x = c & 7;
            *(f16x8*)&Vs[d][x * 8] = *(const f16x8*)&Vt[((size_t)h * 128 + d) * SEQ + c0 + x * 8];
        }
        __syncthreads();

        f32x4 s[4];
#pragma unroll
        for (int ni = 0; ni < 4; ni++) {
            s[ni] = vzero;
            const f16* kp = &Ks_[ni * 16 + l15][0];
#pragma unroll
            for (int kf = 0; kf < 6; kf++)
                s[ni] = mfma16(qf[kf], *(const f16x8*)&kp[kf * 32 + lg * 8], s[ni]);
        }

#pragma unroll
        for (int ni = 0; ni < 4; ni++) {
            const int col = c0 + ni * 16 + l15;
#pragma unroll
            for (int r = 0; r < 4; r++) {
                const int row = rowb + lg * 4 + r;
                float p = (col <= row) ? expf(s[ni][r] - mr[r]) * rlr[r] : 0.f;
                __builtin_nontemporal_store(p, &attnw[((size_t)h * SEQ + row) * SEQ + col]);
                Plds[wv][lg * 4 + r][ni * 16 + l15] = (f16)p;
            }
        }
        asm volatile("" ::: "memory");

        f16x8 pa0 = *(const f16x8*)&Plds[wv][l15][lg * 8];
        f16x8 pa1 = *(const f16x8*)&Plds[wv][l15][32 + lg * 8];
#pragma unroll
        for (int nd = 0; nd < 8; nd++) {
            const f16* vp = &Vs[nd * 16 + l15][lg * 8];
            o[nd] = mfma16(pa0, *(const f16x8*)&vp[0],  o[nd]);
            o[nd] = mfma16(pa1, *(const f16x8*)&vp[32], o[nd]);
        }
    }

#pragma unroll
    for (int nd = 0; nd < 8; nd++)
#pragma unroll
        for (int r = 0; r < 4; r++) {
            const int row = rowb + lg * 4 + r;
            Opart[((size_t)ks * SEQ + row) * 2048 + h * 128 + nd * 16 + l15] = (f16)o[nd][r];
        }

    if (ks == KS - 1) {
        const int cstart = q0 + 64;
        const int zc = SEQ - cstart;
        if (zc > 0) {
            const int nchunk = zc >> 2;
            for (int i = tid; i < 64 * nchunk; i += 256) {
                const int r  = i / nchunk;
                const int cc = (i - r * nchunk) << 2;
                __builtin_nontemporal_store(vzero,
                    (f32x4*)&attnw[((size_t)h * SEQ + q0 + r) * SEQ + cstart + cc]);
            }
        }
    }
}

// ---------------- attention 4/4: combine partial O -> Ohead (f16) ----------------
__global__ __launch_bounds__(256) void k_ocomb(const f16* __restrict__ Opart, f16* __restrict__ Ohead)
{
    size_t i = ((size_t)blockIdx.x * 256 + threadIdx.x) * 8;   // over 2048*2048
    f16x8 a = *(const f16x8*)&Opart[i];
    f16x8 b = *(const f16x8*)&Opart[(size_t)SEQ * 2048 + i];
    f16x8 o;
#pragma unroll
    for (int k = 0; k < 8; k++) o[k] = (f16)((float)a[k] + (float)b[k]);
    *(f16x8*)&Ohead[i] = o;
}

extern "C" void kernel_launch(void* const* d_in, const int* in_sizes, int n_in,
                              void* d_out, int out_size, void* d_ws, size_t ws_size,
                              hipStream_t stream)
{
    (void)in_sizes; (void)n_in; (void)out_size; (void)ws_size;
    const float* hidden    = (const float*)d_in[0];
    const float* q_down_w  = (const float*)d_in[3];
    const float* kv_down_w = (const float*)d_in[4];
    const float* q_up_w    = (const float*)d_in[5];
    const float* k_up_w    = (const float*)d_in[6];
    const float* o_w       = (const float*)d_in[7];
    const float* q_norm_w  = (const float*)d_in[8];
    const float* kv_norm_w = (const float*)d_in[9];

    float* attnw = (float*)d_out;                        // 16*2048*2048 f32
    float* outp  = attnw + (size_t)NHEAD * SEQ * SEQ;    // 2048*2048 f32

    // ---- ws layout: live-late buffers first, then buffers dead before o_proj ----
    char* wp = (char*)d_ws;
    auto aws = [&](size_t bytes) { void* p = (void*)wp; wp += (bytes + 255) & ~(size_t)255; return p; };
    f16*  ow16  = (f16*)aws((size_t)2048 * 2048 * 2);
    f16*  Ohead = (f16*)aws((size_t)2048 * 2048 * 2);
    // dead-before-o_proj region starts here (aliased by opp):
    f16*  Qf    = (f16*)aws((size_t)16 * 2048 * 192 * 2);
    f16*  Knope = (f16*)aws((size_t)16 * 2048 * 128 * 2);
    f16*  Vt    = (f16*)aws((size_t)16 * 128 * 2048 * 2);
    f16*  Krope = (f16*)aws((size_t)2048 * 64 * 2);
    float* cs   = (float*)aws((size_t)2048 * 64 * 4);
    float* mlbuf  = (float*)aws((size_t)16 * 2048 * 2 * 4);
    float* mlpart = (float*)aws((size_t)16 * 32 * KSS * 64 * 2 * 4);
    f16*  Opart   = (f16*)aws((size_t)KS * 2048 * 2048 * 2);
    float* opp    = (float*)Qf;   // o_proj split-K partials [2][2048][2048] f32

    // ---- early-pipeline scratch inside d_out attn region (dead before attention) ----
    char* sp = (char*)d_out;
    auto aso = [&](size_t bytes) { void* p = (void*)sp; sp += (bytes + 255) & ~(size_t)255; return p; };
    f16*  h16      = (f16*)aso((size_t)2048 * 2048 * 2);
    f16*  dw16     = (f16*)aso((size_t)2176 * 2048 * 2);   // q_down(1536) | kv_down(576+64 pad)
    f16*  quw16    = (f16*)aso((size_t)3072 * 1536 * 2);
    f16*  kuw16    = (f16*)aso((size_t)4096 * 512 * 2);
    float* down_part = (float*)aso((size_t)2 * 2048 * 2176 * 4);  // split-K partials
    f16*  cq16     = (f16*)aso((size_t)2048 * 1536 * 2);
    f16*  latent16 = (f16*)aso((size_t)2048 * 512 * 2);
    f16*  q_all    = (f16*)aso((size_t)2048 * 3072 * 2);
    f16*  kv_all   = (f16*)aso((size_t)2048 * 4096 * 2);

    k_rope_table<<<dim3(256), dim3(256), 0, stream>>>(cs);

    k_cvt_all<<<dim3(19200), dim3(256), 0, stream>>>(
        hidden, q_down_w, kv_down_w, q_up_w, k_up_w, o_w,
        h16, dw16, quw16, kuw16, ow16);

    // fused down-projection, split-K=2: partials [2][2048][2176] f32
    k_gemm<float, false, 2><<<dim3(17, 16, 2), dim3(256), 0, stream>>>(
        h16, dw16, down_part, 2048, 2176, (size_t)2048 * 2176);

    k_rms_both<<<dim3(2048), dim3(256), 0, stream>>>(
        down_part, down_part + (size_t)2048 * 2176, q_norm_w, kv_norm_w,
        cq16, latent16, Krope, cs);

    k_up_fused<<<dim3(56, 16), dim3(256), 0, stream>>>(cq16, quw16, q_all, latent16, kuw16, kv_all);

    k_asm_q<<<dim3((16 * 2048 * 192) / 256), dim3(256), 0, stream>>>(q_all, cs, Qf);
    k_asm_kv<<<dim3(16, 16), dim3(256), 0, stream>>>(kv_all, Knope, Vt);

    // attention: stats(KSS=4) -> combine -> P+partialO(KS=2) -> combine O
    k_stats<<<dim3(32, KSS, 16), dim3(256), 0, stream>>>(Qf, Krope, Knope, mlpart);
    k_mlcomb<<<dim3(128), dim3(256), 0, stream>>>(mlpart, mlbuf);
    k_pv<<<dim3(32, KS, 16), dim3(256), 0, stream>>>(Qf, Krope, Knope, Vt, mlbuf, attnw, Opart);
    k_ocomb<<<dim3(2048), dim3(256), 0, stream>>>(Opart, Ohead);

    // output projection, split-K=2 into opp, then combine to f32 outp
    k_gemm<float, false, 2><<<dim3(16, 16, 2), dim3(256), 0, stream>>>(
        Ohead, ow16, opp, 2048, 2048, (size_t)2048 * 2048);
    k_add2f<<<dim3(4096), dim3(256), 0, stream>>>(opp, outp);
}

// Round 8
// 376.245 us; speedup vs baseline: 1.0580x; 1.0580x over previous
//
#include <hip/hip_runtime.h>
#include <cstdint>
#include <cmath>

typedef _Float16 f16;
using f16x8 = __attribute__((ext_vector_type(8))) _Float16;
using f16x4 = __attribute__((ext_vector_type(4))) _Float16;
using f32x4 = __attribute__((ext_vector_type(4))) float;

#define NHEAD 16
#define SEQ   2048
#define KS    2            // K-split factor for attention kernels
#define NEG_INF -3.0e38f

static __device__ __forceinline__ f32x4 mfma16(f16x8 a, f16x8 b, f32x4 c) {
    return __builtin_amdgcn_mfma_f32_16x16x32_f16(a, b, c, 0, 0, 0);
}

static __device__ __forceinline__ void gload16(const void* gp, void* lp) {
    __builtin_amdgcn_global_load_lds(
        (const __attribute__((address_space(1))) unsigned int*)gp,
        (__attribute__((address_space(3))) unsigned int*)lp, 16, 0, 0);
}

// ---------------- fused f32 -> f16 conversion of all 6 tensors ----------------
__global__ __launch_bounds__(256) void k_cvt_all(
    const float* __restrict__ hsrc, const float* __restrict__ qdw, const float* __restrict__ kvdw,
    const float* __restrict__ quw, const float* __restrict__ kuw, const float* __restrict__ ow,
    f16* __restrict__ h16, f16* __restrict__ dw16, f16* __restrict__ quw16,
    f16* __restrict__ kuw16, f16* __restrict__ ow16)
{
    constexpr int C1 = 1048576;            // h: 4194304
    constexpr int C2 = C1 + 786432;        // qdw: 3145728
    constexpr int C3 = C2 + 327680;        // kvdw: 1310720 total (1179648 valid)
    constexpr int C4 = C3 + 1179648;       // quw: 4718592
    constexpr int C5 = C4 + 524288;        // kuw: 2097152
    int chunk = blockIdx.x * 256 + threadIdx.x;
    const float* src; f16* dst; int off; int nvalid;
    if (chunk < C1)      { src = hsrc; dst = h16;  off = chunk;      nvalid = 4194304; }
    else if (chunk < C2) { src = qdw;  dst = dw16; off = chunk - C1; nvalid = 3145728; }
    else if (chunk < C3) { src = kvdw; dst = dw16 + 3145728; off = chunk - C2; nvalid = 1179648; }
    else if (chunk < C4) { src = quw;  dst = quw16; off = chunk - C3; nvalid = 4718592; }
    else if (chunk < C5) { src = kuw;  dst = kuw16; off = chunk - C4; nvalid = 2097152; }
    else                 { src = ow;   dst = ow16;  off = chunk - C5; nvalid = 4194304; }
    int i = off * 4;
    f16x4 o;
#pragma unroll
    for (int k = 0; k < 4; k++) {
        int idx = i + k;
        float v = (idx < nvalid) ? src[idx] : 0.f;
        o[k] = (f16)v;
    }
    *(f16x4*)&dst[i] = o;
}

// ---------------- RoPE cos/sin table ----------------
__global__ __launch_bounds__(256) void k_rope_table(float* __restrict__ cs)
{
    int idx = blockIdx.x * 256 + threadIdx.x;   // 65536 total
    int t = idx >> 5;
    int j = idx & 31;
    float invf = (float)pow(10000.0, -(double)j / 32.0);
    float ang  = (float)t * invf;
    cs[t * 64 + j]      = (float)cos((double)ang);
    cs[t * 64 + 32 + j] = (float)sin((double)ang);
}

// ---------------- GEMM body: BK=64, XOR-swizzled LDS (T2), single-buffered ----------------
// lds: As[128][64] | Bs[128][64] (32 KB). LDS slot (row, chunk c) holds global
// chunk c ^ (row&7); staging pre-swizzles the GLOBAL source (linear LDS dest, rule #21).
template <typename OutT, bool NT>
static __device__ __forceinline__ void gemm_body(const f16* __restrict__ A, const f16* __restrict__ B,
                                                 OutT* __restrict__ C, int K, int ldc,
                                                 int m0, int n0, int k0, int k1,
                                                 f16* __restrict__ lds)
{
    const int tid  = threadIdx.x;
    const int lane = tid & 63;
    const int wv   = tid >> 6;
    const int l15  = lane & 15;
    const int lg   = lane >> 4;
    const int wm   = (wv >> 1) * 64;
    const int wn   = (wv & 1) * 64;

    f32x4 acc[4][4] = {};

    f16* As = lds;           // 8192 f16
    f16* Bs = lds + 8192;

    // staging: pass p covers rows p*32..p*32+31; thread handles row p*32+(tid>>3),
    // source chunk g = (tid&7) ^ ((tid>>3)&7)  (thread-constant swizzle)
    const int srow = tid >> 3;                  // 0..31
    const int g    = (tid & 7) ^ (srow & 7);
    const f16* ap = &A[(size_t)(m0 + srow) * K + g * 8];
    const f16* bp = &B[(size_t)(n0 + srow) * K + g * 8];
    const int ldst = wv * 512;                  // wave-uniform dest offset within pass

    for (int kt = k0; kt < k1; kt += 64) {
        __syncthreads();                        // prior reads done before overwrite
#pragma unroll
        for (int p = 0; p < 4; p++) {
            gload16(ap + (size_t)(p * 32) * K + kt, As + p * 2048 + ldst);
            gload16(bp + (size_t)(p * 32) * K + kt, Bs + p * 2048 + ldst);
        }
        __syncthreads();                        // drains vmcnt(0): tile resident
#pragma unroll
        for (int ki = 0; ki < 2; ki++) {
            f16x8 af[4], bf[4];
#pragma unroll
            for (int i = 0; i < 4; i++) {
                const int ar = wm + i * 16 + l15;
                af[i] = *(const f16x8*)&As[ar * 64 + (((ki * 4 + lg) ^ (ar & 7)) << 3)];
            }
#pragma unroll
            for (int i = 0; i < 4; i++) {
                const int br = wn + i * 16 + l15;
                bf[i] = *(const f16x8*)&Bs[br * 64 + (((ki * 4 + lg) ^ (br & 7)) << 3)];
            }
#pragma unroll
            for (int i = 0; i < 4; i++)
#pragma unroll
                for (int j = 0; j < 4; j++)
                    acc[i][j] = mfma16(af[i], bf[j], acc[i][j]);
        }
    }
#pragma unroll
    for (int i = 0; i < 4; i++) {
#pragma unroll
        for (int j = 0; j < 4; j++) {
            const int row = m0 + wm + i * 16 + lg * 4;
            const int col = n0 + wn + j * 16 + l15;
#pragma unroll
            for (int r = 0; r < 4; r++) {
                if constexpr (NT)
                    __builtin_nontemporal_store((OutT)acc[i][j][r], &C[(size_t)(row + r) * ldc + col]);
                else
                    C[(size_t)(row + r) * ldc + col] = (OutT)acc[i][j][r];
            }
        }
    }
}

// generic GEMM with optional K-split (partials at C + z*zstride)
template <typename OutT, bool NT, int SPLITK>
__global__ __launch_bounds__(256) void k_gemm(const f16* __restrict__ A, const f16* __restrict__ B,
                                              OutT* __restrict__ C, int K, int ldc, size_t zstride)
{
    __shared__ __align__(16) f16 lds[16384];
    const int ks   = (SPLITK > 1) ? (int)blockIdx.z : 0;
    const int ksub = K / SPLITK;
    gemm_body<OutT, NT>(A, B, C + (size_t)ks * zstride, K, ldc,
                        blockIdx.y * 128, blockIdx.x * 128, ks * ksub, ks * ksub + ksub, lds);
}

// fused q_up (24 x-tiles) + k_up (32 x-tiles) launch
__global__ __launch_bounds__(256) void k_up_fused(const f16* __restrict__ cq, const f16* __restrict__ quw,
                                                  f16* __restrict__ q_all,
                                                  const f16* __restrict__ lat, const f16* __restrict__ kuw,
                                                  f16* __restrict__ kv_all)
{
    __shared__ __align__(16) f16 lds[16384];
    if (blockIdx.x < 24)
        gemm_body<f16, false>(cq, quw, q_all, 1536, 3072,
                              blockIdx.y * 128, blockIdx.x * 128, 0, 1536, lds);
    else
        gemm_body<f16, false>(lat, kuw, kv_all, 512, 4096,
                              blockIdx.y * 128, (blockIdx.x - 24) * 128, 0, 512, lds);
}

// ---------------- o_proj split-K combine ----------------
__global__ __launch_bounds__(256) void k_add2f(const float* __restrict__ p, float* __restrict__ out)
{
    size_t i = ((size_t)blockIdx.x * 256 + threadIdx.x) * 4;
    f32x4 a = *(const f32x4*)&p[i];
    f32x4 b = *(const f32x4*)&p[(size_t)2048 * 2048 + i];
    __builtin_nontemporal_store(a + b, (f32x4*)&out[i]);
}

// ---------------- fused RMS norms + down split-K combine + k_pe rope ----------------
__global__ __launch_bounds__(256) void k_rms_both(const float* __restrict__ P0, const float* __restrict__ P1,
                                                  const float* __restrict__ wq, const float* __restrict__ wkv,
                                                  f16* __restrict__ cq, f16* __restrict__ lat,
                                                  f16* __restrict__ kro, const float* __restrict__ cs)
{
    const int row = blockIdx.x, tid = threadIdx.x;
    const float* a = &P0[(size_t)row * 2176];
    const float* b = &P1[(size_t)row * 2176];
    float ssq = 0.f, ssk = 0.f;
    for (int c = tid; c < 1536; c += 256) { float v = a[c] + b[c]; ssq += v * v; }
    for (int c = 1536 + tid; c < 2112; c += 256) { float v = a[c] + b[c]; ssk += v * v; }
#pragma unroll
    for (int off = 32; off > 0; off >>= 1) {
        ssq += __shfl_xor(ssq, off);
        ssk += __shfl_xor(ssk, off);
    }
    __shared__ float part[4][2];
    if ((tid & 63) == 0) { part[tid >> 6][0] = ssq; part[tid >> 6][1] = ssk; }
    __syncthreads();
    float totq = part[0][0] + part[1][0] + part[2][0] + part[3][0];
    float totk = part[0][1] + part[1][1] + part[2][1] + part[3][1];
    float scq = 1.f / sqrtf(totq / 1536.f + 1e-6f);
    float sck = 1.f / sqrtf(totk / 576.f + 1e-6f);
    for (int c = tid; c < 1536; c += 256)
        cq[(size_t)row * 1536 + c] = (f16)(wq[c] * (a[c] + b[c]) * scq);
    for (int c = tid; c < 512; c += 256)
        lat[(size_t)row * 512 + c] = (f16)(wkv[c] * (a[1536 + c] + b[1536 + c]) * sck);
    if (tid < 32) {
        int j = tid;
        float va = wkv[512 + 2 * j] * (a[2048 + 2 * j] + b[2048 + 2 * j]) * sck;
        float vb = wkv[512 + 2 * j + 1] * (a[2048 + 2 * j + 1] + b[2048 + 2 * j + 1]) * sck;
        float cv = cs[row * 64 + j], sv = cs[row * 64 + 32 + j];
        kro[row * 64 + j]      = (f16)(va * cv - vb * sv);
        kro[row * 64 + 32 + j] = (f16)(vb * cv + va * sv);
    }
}

// ---------------- assemble Q ----------------
__global__ __launch_bounds__(256) void k_asm_q(const f16* __restrict__ q_all, const float* __restrict__ cs,
                                               f16* __restrict__ Qf)
{
    size_t idx = (size_t)blockIdx.x * 256 + threadIdx.x;
    if (idx >= (size_t)16 * 2048 * 192) return;
    int d = (int)(idx % 192);
    size_t hs = idx / 192;
    int s = (int)(hs % 2048);
    int h = (int)(hs / 2048);
    const f16* qrow = &q_all[(size_t)s * 3072 + h * 192];
    float v;
    if (d < 64) {
        int j = d & 31;
        float a = (float)qrow[128 + 2 * j], b = (float)qrow[128 + 2 * j + 1];
        float cv = cs[s * 64 + j], sv = cs[s * 64 + 32 + j];
        v = (d < 32) ? (a * cv - b * sv) : (b * cv + a * sv);
    } else {
        v = (float)qrow[d - 64];
    }
    Qf[idx] = (f16)v;
}

// ---------------- assemble K_nope + V^T via LDS transpose ----------------
__global__ __launch_bounds__(256) void k_asm_kv(const f16* __restrict__ kv_all,
                                                f16* __restrict__ Knope,  // [16][2048][128]
                                                f16* __restrict__ Vt)     // [16][128][2048]
{
    __shared__ __align__(16) f16 Vs[128][136];
    const int s0 = blockIdx.x * 128;
    const int h  = blockIdx.y;
    const int tid = threadIdx.x;

#pragma unroll
    for (int i = 0; i < 16; i++) {
        const int c = tid + 256 * i;
        const int s_loc = c >> 5;
        const int g = c & 31;
        f16x8 v = *(const f16x8*)&kv_all[(size_t)(s0 + s_loc) * 4096 + h * 256 + g * 8];
        if (g < 16) {
            *(f16x8*)&Knope[((size_t)h * 2048 + s0 + s_loc) * 128 + g * 8] = v;
        } else {
            const int d0 = (g - 16) * 8;
#pragma unroll
            for (int k = 0; k < 8; k++) Vs[d0 + k][s_loc] = v[k];
        }
    }
    __syncthreads();
#pragma unroll
    for (int i = 0; i < 8; i++) {
        const int c = tid + 256 * i;
        const int d = c >> 4;
        const int gs = c & 15;
        f16x8 v = *(const f16x8*)&Vs[d][gs * 8];
        *(f16x8*)&Vt[((size_t)h * 128 + d) * 2048 + s0 + gs * 8] = v;
    }
}

// ---------------- attention 1/4: K-split partial softmax stats ----------------
__global__ __launch_bounds__(256) void k_stats(
    const f16* __restrict__ Qf, const f16* __restrict__ Krope, const f16* __restrict__ Knope,
    float* __restrict__ mlpart)   // [16][32][KS][64][2]
{
    const int h  = blockIdx.z;
    const int ks = blockIdx.y;
    const int qt = blockIdx.x;
    const int q0 = qt * 64;
    const int tid = threadIdx.x;
    const int lane = tid & 63;
    const int wv = tid >> 6;
    const int l15 = lane & 15;
    const int lg  = lane >> 4;
    const int rowb = q0 + wv * 16;

    __shared__ __align__(16) f16 Ks_[64][200];

    f16x8 qf[6];
    {
        const f16* qbase = &Qf[((size_t)h * SEQ + rowb + l15) * 192];
#pragma unroll
        for (int kf = 0; kf < 6; kf++)
            qf[kf] = *(const f16x8*)&qbase[kf * 32 + lg * 8];
    }

    float m[4], l[4];
#pragma unroll
    for (int r = 0; r < 4; r++) { m[r] = NEG_INF; l[r] = 0.f; }

    const int srow = tid >> 2;
    const int sp4  = tid & 3;
    const f32x4 vzero = {0.f, 0.f, 0.f, 0.f};

    for (int t = ks; t <= qt; t += KS) {
        const int c0 = t * 64;
        __syncthreads();
#pragma unroll
        for (int i = 0; i < 6; i++) {
            const int p = sp4 + 4 * i;
            f16x8 v;
            if (p < 8) v = *(const f16x8*)&Krope[(size_t)(c0 + srow) * 64 + p * 8];
            else       v = *(const f16x8*)&Knope[((size_t)h * SEQ + c0 + srow) * 128 + (p - 8) * 8];
            *(f16x8*)&Ks_[srow][p * 8] = v;
        }
        __syncthreads();

        f32x4 s[4];
#pragma unroll
        for (int ni = 0; ni < 4; ni++) {
            s[ni] = vzero;
            const f16* kp = &Ks_[ni * 16 + l15][0];
#pragma unroll
            for (int kf = 0; kf < 6; kf++)
                s[ni] = mfma16(qf[kf], *(const f16x8*)&kp[kf * 32 + lg * 8], s[ni]);
        }

        float vmax[4] = {NEG_INF, NEG_INF, NEG_INF, NEG_INF};
#pragma unroll
        for (int ni = 0; ni < 4; ni++) {
            const int col = c0 + ni * 16 + l15;
#pragma unroll
            for (int r = 0; r < 4; r++) {
                const int row = rowb + lg * 4 + r;
                float v = (col <= row) ? s[ni][r] : NEG_INF;
                s[ni][r] = v;
                vmax[r] = fmaxf(vmax[r], v);
            }
        }
#pragma unroll
        for (int off = 1; off < 16; off <<= 1)
#pragma unroll
            for (int r = 0; r < 4; r++)
                vmax[r] = fmaxf(vmax[r], __shfl_xor(vmax[r], off));
#pragma unroll
        for (int r = 0; r < 4; r++) {
            const float nm = fmaxf(m[r], vmax[r]);
            float es = 0.f;
#pragma unroll
            for (int ni = 0; ni < 4; ni++) es += expf(s[ni][r] - nm);
#pragma unroll
            for (int off = 1; off < 16; off <<= 1) es += __shfl_xor(es, off);
            l[r] = l[r] * expf(m[r] - nm) + es;
            m[r] = nm;
        }
    }

    if (l15 == 0) {
#pragma unroll
        for (int r = 0; r < 4; r++) {
            const int rin = wv * 16 + lg * 4 + r;
            float* mp = &mlpart[((((size_t)h * 32 + qt) * KS + ks) * 64 + rin) * 2];
            mp[0] = m[r];
            mp[1] = l[r];
        }
    }
}

// ---------------- attention 2/4: merge partial (m,l) -> (m, 1/l) ----------------
__global__ __launch_bounds__(256) void k_mlcomb(const float* __restrict__ mlpart,
                                                float* __restrict__ mlbuf)
{
    int idx = blockIdx.x * 256 + threadIdx.x;      // 16*2048
    if (idx >= 16 * 2048) return;
    int h = idx >> 11, row = idx & 2047;
    int qt = row >> 6, rin = row & 63;
    float mm = NEG_INF;
    float mk[KS], lk[KS];
#pragma unroll
    for (int ks = 0; ks < KS; ks++) {
        const float* mp = &mlpart[((((size_t)h * 32 + qt) * KS + ks) * 64 + rin) * 2];
        mk[ks] = mp[0]; lk[ks] = mp[1];
        mm = fmaxf(mm, mk[ks]);
    }
    float ll = 0.f;
#pragma unroll
    for (int ks = 0; ks < KS; ks++) ll += lk[ks] * expf(mk[ks] - mm);
    mlbuf[(size_t)idx * 2]     = mm;
    mlbuf[(size_t)idx * 2 + 1] = 1.f / ll;
}

// ---------------- attention 3/4: P write (nt) + partial O ----------------
__global__ __launch_bounds__(256) void k_pv(
    const f16* __restrict__ Qf, const f16* __restrict__ Krope, const f16* __restrict__ Knope,
    const f16* __restrict__ Vt, const float* __restrict__ mlbuf,
    float* __restrict__ attnw,    // [16][2048][2048] final P
    f16* __restrict__ Opart)      // [KS][2048][2048] partial O
{
    const int h  = blockIdx.z;
    const int ks = blockIdx.y;
    const int qt = blockIdx.x;
    const int q0 = qt * 64;
    const int tid = threadIdx.x;
    const int lane = tid & 63;
    const int wv = tid >> 6;
    const int l15 = lane & 15;
    const int lg  = lane >> 4;
    const int rowb = q0 + wv * 16;

    __shared__ __align__(16) f16 Ks_[64][200];
    __shared__ __align__(16) f16 Vs[128][72];
    __shared__ __align__(16) f16 Plds[4][16][72];

    f16x8 qf[6];
    {
        const f16* qbase = &Qf[((size_t)h * SEQ + rowb + l15) * 192];
#pragma unroll
        for (int kf = 0; kf < 6; kf++)
            qf[kf] = *(const f16x8*)&qbase[kf * 32 + lg * 8];
    }

    float mr[4], rlr[4];
#pragma unroll
    for (int r = 0; r < 4; r++) {
        const int row = rowb + lg * 4 + r;
        mr[r]  = mlbuf[((size_t)h * SEQ + row) * 2];
        rlr[r] = mlbuf[((size_t)h * SEQ + row) * 2 + 1];
    }

    f32x4 o[8] = {};
    const f32x4 vzero = {0.f, 0.f, 0.f, 0.f};
    const int srow = tid >> 2;
    const int sp4  = tid & 3;

    for (int t = ks; t <= qt; t += KS) {
        const int c0 = t * 64;
        __syncthreads();
#pragma unroll
        for (int i = 0; i < 6; i++) {
            const int p = sp4 + 4 * i;
            f16x8 v;
            if (p < 8) v = *(const f16x8*)&Krope[(size_t)(c0 + srow) * 64 + p * 8];
            else       v = *(const f16x8*)&Knope[((size_t)h * SEQ + c0 + srow) * 128 + (p - 8) * 8];
            *(f16x8*)&Ks_[srow][p * 8] = v;
        }
#pragma unroll
        for (int i = 0; i < 4; i++) {
            const int c = tid + 256 * i;
            const int d = c >> 3, x = c & 7;
            *(f16x8*)&Vs[d][x * 8] = *(const f16x8*)&Vt[((size_t)h * 128 + d) * SEQ + c0 + x * 8];
        }
        __syncthreads();

        f32x4 s[4];
#pragma unroll
        for (int ni = 0; ni < 4; ni++) {
            s[ni] = vzero;
            const f16* kp = &Ks_[ni * 16 + l15][0];
#pragma unroll
            for (int kf = 0; kf < 6; kf++)
                s[ni] = mfma16(qf[kf], *(const f16x8*)&kp[kf * 32 + lg * 8], s[ni]);
        }

#pragma unroll
        for (int ni = 0; ni < 4; ni++) {
            const int col = c0 + ni * 16 + l15;
#pragma unroll
            for (int r = 0; r < 4; r++) {
                const int row = rowb + lg * 4 + r;
                float p = (col <= row) ? expf(s[ni][r] - mr[r]) * rlr[r] : 0.f;
                __builtin_nontemporal_store(p, &attnw[((size_t)h * SEQ + row) * SEQ + col]);
                Plds[wv][lg * 4 + r][ni * 16 + l15] = (f16)p;
            }
        }
        asm volatile("" ::: "memory");

        f16x8 pa0 = *(const f16x8*)&Plds[wv][l15][lg * 8];
        f16x8 pa1 = *(const f16x8*)&Plds[wv][l15][32 + lg * 8];
#pragma unroll
        for (int nd = 0; nd < 8; nd++) {
            const f16* vp = &Vs[nd * 16 + l15][lg * 8];
            o[nd] = mfma16(pa0, *(const f16x8*)&vp[0],  o[nd]);
            o[nd] = mfma16(pa1, *(const f16x8*)&vp[32], o[nd]);
        }
    }

#pragma unroll
    for (int nd = 0; nd < 8; nd++)
#pragma unroll
        for (int r = 0; r < 4; r++) {
            const int row = rowb + lg * 4 + r;
            Opart[((size_t)ks * SEQ + row) * 2048 + h * 128 + nd * 16 + l15] = (f16)o[nd][r];
        }

    if (ks == KS - 1) {
        const int cstart = q0 + 64;
        const int zc = SEQ - cstart;
        if (zc > 0) {
            const int nchunk = zc >> 2;
            for (int i = tid; i < 64 * nchunk; i += 256) {
                const int r  = i / nchunk;
                const int cc = (i - r * nchunk) << 2;
                __builtin_nontemporal_store(vzero,
                    (f32x4*)&attnw[((size_t)h * SEQ + q0 + r) * SEQ + cstart + cc]);
            }
        }
    }
}

// ---------------- attention 4/4: combine partial O -> Ohead (f16) ----------------
__global__ __launch_bounds__(256) void k_ocomb(const f16* __restrict__ Opart, f16* __restrict__ Ohead)
{
    size_t i = ((size_t)blockIdx.x * 256 + threadIdx.x) * 8;   // over 2048*2048
    f16x8 a = *(const f16x8*)&Opart[i];
    f16x8 b = *(const f16x8*)&Opart[(size_t)SEQ * 2048 + i];
    f16x8 o;
#pragma unroll
    for (int k = 0; k < 8; k++) o[k] = (f16)((float)a[k] + (float)b[k]);
    *(f16x8*)&Ohead[i] = o;
}

extern "C" void kernel_launch(void* const* d_in, const int* in_sizes, int n_in,
                              void* d_out, int out_size, void* d_ws, size_t ws_size,
                              hipStream_t stream)
{
    (void)in_sizes; (void)n_in; (void)out_size; (void)ws_size;
    const float* hidden    = (const float*)d_in[0];
    const float* q_down_w  = (const float*)d_in[3];
    const float* kv_down_w = (const float*)d_in[4];
    const float* q_up_w    = (const float*)d_in[5];
    const float* k_up_w    = (const float*)d_in[6];
    const float* o_w       = (const float*)d_in[7];
    const float* q_norm_w  = (const float*)d_in[8];
    const float* kv_norm_w = (const float*)d_in[9];

    float* attnw = (float*)d_out;                        // 16*2048*2048 f32
    float* outp  = attnw + (size_t)NHEAD * SEQ * SEQ;    // 2048*2048 f32

    // ---- ws layout: live-late buffers first, then buffers dead before o_proj ----
    char* wp = (char*)d_ws;
    auto aws = [&](size_t bytes) { void* p = (void*)wp; wp += (bytes + 255) & ~(size_t)255; return p; };
    f16*  ow16  = (f16*)aws((size_t)2048 * 2048 * 2);
    f16*  Ohead = (f16*)aws((size_t)2048 * 2048 * 2);
    // dead-before-o_proj region starts here (aliased by opp):
    f16*  Qf    = (f16*)aws((size_t)16 * 2048 * 192 * 2);
    f16*  Knope = (f16*)aws((size_t)16 * 2048 * 128 * 2);
    f16*  Vt    = (f16*)aws((size_t)16 * 128 * 2048 * 2);
    f16*  Krope = (f16*)aws((size_t)2048 * 64 * 2);
    float* cs   = (float*)aws((size_t)2048 * 64 * 4);
    float* mlbuf  = (float*)aws((size_t)16 * 2048 * 2 * 4);
    float* mlpart = (float*)aws((size_t)16 * 32 * KS * 64 * 2 * 4);
    f16*  Opart   = (f16*)aws((size_t)KS * 2048 * 2048 * 2);
    float* opp    = (float*)Qf;   // o_proj split-K partials [2][2048][2048] f32

    // ---- early-pipeline scratch inside d_out attn region (dead before attention) ----
    char* sp = (char*)d_out;
    auto aso = [&](size_t bytes) { void* p = (void*)sp; sp += (bytes + 255) & ~(size_t)255; return p; };
    f16*  h16      = (f16*)aso((size_t)2048 * 2048 * 2);
    f16*  dw16     = (f16*)aso((size_t)2176 * 2048 * 2);   // q_down(1536) | kv_down(576+64 pad)
    f16*  quw16    = (f16*)aso((size_t)3072 * 1536 * 2);
    f16*  kuw16    = (f16*)aso((size_t)4096 * 512 * 2);
    float* down_part = (float*)aso((size_t)2 * 2048 * 2176 * 4);  // split-K partials
    f16*  cq16     = (f16*)aso((size_t)2048 * 1536 * 2);
    f16*  latent16 = (f16*)aso((size_t)2048 * 512 * 2);
    f16*  q_all    = (f16*)aso((size_t)2048 * 3072 * 2);
    f16*  kv_all   = (f16*)aso((size_t)2048 * 4096 * 2);

    k_rope_table<<<dim3(256), dim3(256), 0, stream>>>(cs);

    k_cvt_all<<<dim3(19200), dim3(256), 0, stream>>>(
        hidden, q_down_w, kv_down_w, q_up_w, k_up_w, o_w,
        h16, dw16, quw16, kuw16, ow16);

    // fused down-projection, split-K=2: partials [2][2048][2176] f32
    k_gemm<float, false, 2><<<dim3(17, 16, 2), dim3(256), 0, stream>>>(
        h16, dw16, down_part, 2048, 2176, (size_t)2048 * 2176);

    k_rms_both<<<dim3(2048), dim3(256), 0, stream>>>(
        down_part, down_part + (size_t)2048 * 2176, q_norm_w, kv_norm_w,
        cq16, latent16, Krope, cs);

    k_up_fused<<<dim3(56, 16), dim3(256), 0, stream>>>(cq16, quw16, q_all, latent16, kuw16, kv_all);

    k_asm_q<<<dim3((16 * 2048 * 192) / 256), dim3(256), 0, stream>>>(q_all, cs, Qf);
    k_asm_kv<<<dim3(16, 16), dim3(256), 0, stream>>>(kv_all, Knope, Vt);

    // attention: stats -> combine -> P+partialO -> combine O
    k_stats<<<dim3(32, KS, 16), dim3(256), 0, stream>>>(Qf, Krope, Knope, mlpart);
    k_mlcomb<<<dim3(128), dim3(256), 0, stream>>>(mlpart, mlbuf);
    k_pv<<<dim3(32, KS, 16), dim3(256), 0, stream>>>(Qf, Krope, Knope, Vt, mlbuf, attnw, Opart);
    k_ocomb<<<dim3(2048), dim3(256), 0, stream>>>(Opart, Ohead);

    // output projection, split-K=2 into opp, then combine to f32 outp
    k_gemm<float, false, 2><<<dim3(16, 16, 2), dim3(256), 0, stream>>>(
        Ohead, ow16, opp, 2048, 2048, (size_t)2048 * 2048);
    k_add2f<<<dim3(4096), dim3(256), 0, stream>>>(opp, outp);
}